// Round 11
// baseline (130.415 us; speedup 1.0000x reference)
//
#include <hip/hip_runtime.h>
#include <math.h>

// B=2, HD=4, H=W=128, KSIZE=7 (K=49), NSP=9, S=64
#define BN   2
#define HDN  4
#define HN   128
#define WN   128
#define KS   7
#define KK   49
#define NSPN 9
#define TPB  256     // 4 waves; wave = 4 pixels x 4 heads x 4 k-slices
#define PIXSTR 60    // patch pixel stride (dwords)
#define PBUF (4 * PIXSTR)   // 240 dwords per plane buffer (4 patches)

// Compiler-only memory fence (v8-validated discipline for barrier-free
// cross-lane LDS reuse; emits nothing).
#define CFENCE() asm volatile("" ::: "memory")

// v13 = v12's k-split parallelism + v9's ALIGNED staged I/O. v12's direct
// register I/O put lane bases at s*14 dwords (56B): every attn load and out
// store was a misaligned partial-line access -> L2 write-allocate (FETCH 69
// vs 36 MB) and 4.6x write amplification (WRITE 124 vs 27 MB); 59us despite
// 32% occupancy and 3.3 TB/s sustained. v13 stages attn/out through wave-
// private LDS: per hd-plane one aligned float4 round (lanes<49, 196 dwords,
// 16B-aligned because ww0%4==0), per-lane a[14]/z[14] redistribution at
// stride-49 (~2-way banks). Compute/gather/softmax = v12 verbatim (proven).
__global__ __launch_bounds__(TPB, 4) void attn_rw13(
    const float* __restrict__ attn,
    const float* __restrict__ sims,
    const int*   __restrict__ sinds,
    float*       __restrict__ out)
{
    __shared__ __align__(16) float stgm[4][784];        // per-wave attn/out staging (12.5 KB)
    __shared__ __align__(16) float pbm[4][2 * PBUF];    // per-wave patch dbuf (7.7 KB)
    __shared__ int g_lds[4][40];                        // per-wave sinds (36 used)

    const int t    = threadIdx.x;
    const int lane = t & 63;
    const int wv   = t >> 6;
    const int bx   = blockIdx.x;
    const int wseg = bx & 7;                 // 8 x 16-pixel segments
    const int hh   = (bx >> 3) & 127;
    const int b    = bx >> 10;
    const int ww0  = wseg * 16 + wv * 4;     // wave's first absolute column

    const int u   = lane >> 2;               // unit 0..15
    const int s   = lane & 3;                // k-slice: rows {2s, 2s+1}
    const int pix = u >> 2;                  // 0..3
    const int hd  = u & 3;

    const float* simsB = sims + ((size_t)b << 20);
    int hs = hh - 3; hs = max(0, min(HN - KS, hs));
    const int dr = hh - hs;                  // 0..6, block-uniform

    float* stg = stgm[wv];
    float* pb  = pbm[wv];
    int*   gl  = g_lds[wv];

    // ---- sinds: 36 ints, one coalesced int4 round ----
    {
        const int* ssrc = sinds + ((b * HN + hh) * WN + ww0) * NSPN;
        if (lane < 9) {
            int4 sv;
            __builtin_memcpy(&sv, ssrc + lane * 4, 16);
            *(int4*)(gl + lane * 4) = sv;
        }
    }
    CFENCE();                                // gl published (cross-lane consumers)

    // ---- wide-gather lane constants (4 patches in ONE instr) ----
    const int  grp   = min(lane / 14, 3);    // patch (=pixel) slot
    const int  cp    = lane - grp * 14;
    const int  grow  = min(cp >> 1, 6);      // row 0..6
    const int  ghalf = cp & 1;               // 0: cols 0-3, 1: cols 3-6
    const bool gact  = lane < 56;
    const int  wsg   = max(0, min(WN - KS, ww0 + grp - 3));
    const int  rowoff = (hs + grow) * WN + ghalf * 3;

    float4 q;                                // single named in-flight reg
#define ISSUE(sp) { \
        int g_ = gl[grp * NSPN + (sp)]; \
        if (gact) __builtin_memcpy(&q, simsB + ((size_t)g_ << 14) + rowoff + wsg, 16); }
#define GSTORE(buf) { \
        if (gact) *(float4*)(pb + (buf) * PBUF + grp * PIXSTR + grow * 8 + ghalf * 4) = q; }

    ISSUE(0)                                 // in flight under staging + softmax

    // ---- attn staging: 4 aligned float4 rounds (one per hd-plane) ----
    const size_t hwk  = (size_t)HN * WN * KK;
    const size_t sbas = (size_t)(hh * WN + ww0) * KK;    // 16B-aligned (ww0%4==0)
    const float* aB   = attn + (size_t)b * HDN * hwk + sbas;

    {
        float4 t0, t1, t2, t3;
        if (lane < 49) {
            t0 = *(const float4*)(aB + lane * 4);
            t1 = *(const float4*)(aB + hwk + lane * 4);
            t2 = *(const float4*)(aB + 2 * hwk + lane * 4);
            t3 = *(const float4*)(aB + 3 * hwk + lane * 4);
            *(float4*)(stg + lane * 4) = t0;             // hd0 -> [0..195]
            *(float4*)(stg + 196 + lane * 4) = t1;
            *(float4*)(stg + 392 + lane * 4) = t2;
            *(float4*)(stg + 588 + lane * 4) = t3;
        }
    }
    CFENCE();                                // cross-lane RAW: stage -> a[] reads

    // ---- a[14]: per-lane redistribution (stride-49, ~2-way banks) ----
    const int abase = hd * 196 + pix * KK + s * 14;
    float a[14];
    #pragma unroll
    for (int j = 0; j < 14; ++j) {
        float v = -1e30f;                    // s3 ghosts: zero weight after exp
        if (s < 3 || j < 7) v = stg[abase + j];
        a[j] = v;
    }

    // ---- softmax: local max/exp + 4-lane butterfly ----
    {
        float m0 = fmaxf(a[0], a[1]),  m1 = fmaxf(a[2], a[3]);
        float m2 = fmaxf(a[4], a[5]),  m3 = fmaxf(a[6], a[7]);
        m0 = fmaxf(m0, fmaxf(a[8], a[9]));
        m1 = fmaxf(m1, fmaxf(a[10], a[11]));
        m2 = fmaxf(m2, fmaxf(a[12], a[13]));
        float m = fmaxf(fmaxf(m0, m1), fmaxf(m2, m3));
        m = fmaxf(m, __shfl_xor(m, 1));
        m = fmaxf(m, __shfl_xor(m, 2));      // unit max, identical in 4 lanes
        #pragma unroll
        for (int j = 0; j < 14; ++j) a[j] = __expf(a[j] - m);   // ghosts -> 0
    }

    GSTORE(0)

    // ---- compute-view constants ----
    const int prow0 = pix * PIXSTR + (2 * s) * 8;                  // row 2s quads
    const int prow1 = pix * PIXSTR + min(2 * s + 1, 6) * 8;        // row 2s+1 (s3: row6 again)
    const int wabs  = ww0 + pix;
    const int wsp   = max(0, min(WN - KS, wabs - 3));
    const int dc    = wabs - wsp;
    const int pioff = pix * PIXSTR + dr * 8 + dc + (dc > 3 ? 1 : 0);

    float acc[14];
    #pragma unroll
    for (int j = 0; j < 14; ++j) acc[j] = 0.0f;

    for (int sp = 0; sp < NSPN; ++sp) {
        const int buf = sp & 1;
        if (sp + 1 < NSPN) ISSUE(sp + 1)     // next plane in flight
        CFENCE();                            // RAW: gstore(prev)->reads; WAR: reads->gstore below

        const float* pp = pb + buf * PBUF;
        float4 p0 = *(const float4*)(pp + prow0);        // row r0 cols 0-3
        float4 p1 = *(const float4*)(pp + prow0 + 4);    // row r0 cols 3-6
        float4 p2 = *(const float4*)(pp + prow1);        // row r1 cols 0-3
        float4 p3 = *(const float4*)(pp + prow1 + 4);    // row r1 cols 3-6
        float pi  = pp[pioff];

        // partial denom over own 14 k (ghosts contribute 0), 2-way chains
        float d0 = a[0] * p0.x, d1 = a[1] * p0.y;
        d0 = fmaf(a[2],  p0.z, d0); d1 = fmaf(a[3],  p0.w, d1);
        d0 = fmaf(a[4],  p1.y, d0); d1 = fmaf(a[5],  p1.z, d1);
        d0 = fmaf(a[6],  p1.w, d0); d1 = fmaf(a[7],  p2.x, d1);
        d0 = fmaf(a[8],  p2.y, d0); d1 = fmaf(a[9],  p2.z, d1);
        d0 = fmaf(a[10], p2.w, d0); d1 = fmaf(a[11], p3.y, d1);
        d0 = fmaf(a[12], p3.z, d0); d1 = fmaf(a[13], p3.w, d1);
        float d = d0 + d1;
        d += __shfl_xor(d, 1);
        d += __shfl_xor(d, 2);               // full unit denom, identical in 4 lanes

        float coef = pi * __builtin_amdgcn_rcpf(d + 1e-10f);

        acc[0]  = fmaf(coef, p0.x, acc[0]);  acc[1]  = fmaf(coef, p0.y, acc[1]);
        acc[2]  = fmaf(coef, p0.z, acc[2]);  acc[3]  = fmaf(coef, p0.w, acc[3]);
        acc[4]  = fmaf(coef, p1.y, acc[4]);  acc[5]  = fmaf(coef, p1.z, acc[5]);
        acc[6]  = fmaf(coef, p1.w, acc[6]);  acc[7]  = fmaf(coef, p2.x, acc[7]);
        acc[8]  = fmaf(coef, p2.y, acc[8]);  acc[9]  = fmaf(coef, p2.z, acc[9]);
        acc[10] = fmaf(coef, p2.w, acc[10]); acc[11] = fmaf(coef, p3.y, acc[11]);
        acc[12] = fmaf(coef, p3.z, acc[12]); acc[13] = fmaf(coef, p3.w, acc[13]);

        if (sp + 1 < NSPN) GSTORE(buf ^ 1)   // in-wave order; no barrier
    }
#undef ISSUE
#undef GSTORE

    // ---- out: per-lane LDS stage (stride-49) -> 4 aligned float4 rounds ----
    CFENCE();                                // WAR: last patch/pi reads -> stg reuse is disjoint; order stg writes
    #pragma unroll
    for (int j = 0; j < 14; ++j) {
        if (s < 3 || j < 7) stg[abase + j] = a[j] * acc[j];
    }
    CFENCE();                                // cross-lane RAW: writes -> float4 reads

    float* oB = out + (size_t)b * HDN * hwk + sbas;
    if (lane < 49) {
        float4 z0 = *(const float4*)(stg + lane * 4);
        float4 z1 = *(const float4*)(stg + 196 + lane * 4);
        float4 z2 = *(const float4*)(stg + 392 + lane * 4);
        float4 z3 = *(const float4*)(stg + 588 + lane * 4);
        *(float4*)(oB + lane * 4) = z0;
        *(float4*)(oB + hwk + lane * 4) = z1;
        *(float4*)(oB + 2 * hwk + lane * 4) = z2;
        *(float4*)(oB + 3 * hwk + lane * 4) = z3;
    }
}

extern "C" void kernel_launch(void* const* d_in, const int* in_sizes, int n_in,
                              void* d_out, int out_size, void* d_ws, size_t ws_size,
                              hipStream_t stream) {
    const float* attn  = (const float*)d_in[0];
    const float* sims  = (const float*)d_in[1];
    const int*   sinds = (const int*)d_in[2];
    float*       outp  = (float*)d_out;

    // blocks: b(2) x hh(128) x wseg(8) = 2048, 4 waves each (16 pixels/block)
    const int blocks = BN * HN * (WN / 16);
    attn_rw13<<<blocks, TPB, 0, stream>>>(attn, sims, sinds, outp);
}

// Round 12
// 96.956 us; speedup vs baseline: 1.3451x; 1.3451x over previous
//
#include <hip/hip_runtime.h>
#include <math.h>

// B=2, HD=4, H=W=128, KSIZE=7 (K=49), NSP=9, S=64
#define BN   2
#define HDN  4
#define HN   128
#define WN   128
#define KS   7
#define KK   49
#define NSPN 9
#define TPB  256     // 4 waves; wave = 4 pixels x 4 heads x 4 k-slices
#define PIXSTR 60    // patch pixel stride (dwords)
#define PBUF (4 * PIXSTR)   // 240 dwords per plane buffer (4 patches)

// Compiler-only memory fence (v8-validated discipline for barrier-free
// cross-lane LDS reuse; emits nothing).
#define CFENCE() asm volatile("" ::: "memory")

// v14 = v13 with ONE change: __launch_bounds__(256, 2) instead of (256, 4).
// Session-wide unified theory: every dirty-traffic round had VGPR_Count
// pinned at an occupancy step (64 or 128) -- the backend squeezes VGPRs to
// the step and SPILLS the overflow; the spill slots are rewritten every
// sp-iteration (x9) -> the ~85MB WRITE excess + ~40MB FETCH excess seen in
// v12/v13 (and, at 128, v6/v10). Natural live set here is ~75-100 regs;
// min-waves=2 caps VGPR at 256 -> no squeeze, no spill, and still 4 waves/EU
// (<=128 step) = 16 waves/CU resident, 2x the v9 baseline. All compute,
// gather, staging, and fence code is byte-identical to the PASSING v13.
__global__ __launch_bounds__(TPB, 2) void attn_rw14(
    const float* __restrict__ attn,
    const float* __restrict__ sims,
    const int*   __restrict__ sinds,
    float*       __restrict__ out)
{
    __shared__ __align__(16) float stgm[4][784];        // per-wave attn/out staging (12.5 KB)
    __shared__ __align__(16) float pbm[4][2 * PBUF];    // per-wave patch dbuf (7.7 KB)
    __shared__ int g_lds[4][40];                        // per-wave sinds (36 used)

    const int t    = threadIdx.x;
    const int lane = t & 63;
    const int wv   = t >> 6;
    const int bx   = blockIdx.x;
    const int wseg = bx & 7;                 // 8 x 16-pixel segments
    const int hh   = (bx >> 3) & 127;
    const int b    = bx >> 10;
    const int ww0  = wseg * 16 + wv * 4;     // wave's first absolute column

    const int u   = lane >> 2;               // unit 0..15
    const int s   = lane & 3;                // k-slice: rows {2s, 2s+1}
    const int pix = u >> 2;                  // 0..3
    const int hd  = u & 3;

    const float* simsB = sims + ((size_t)b << 20);
    int hs = hh - 3; hs = max(0, min(HN - KS, hs));
    const int dr = hh - hs;                  // 0..6, block-uniform

    float* stg = stgm[wv];
    float* pb  = pbm[wv];
    int*   gl  = g_lds[wv];

    // ---- sinds: 36 ints, one coalesced int4 round ----
    {
        const int* ssrc = sinds + ((b * HN + hh) * WN + ww0) * NSPN;
        if (lane < 9) {
            int4 sv;
            __builtin_memcpy(&sv, ssrc + lane * 4, 16);
            *(int4*)(gl + lane * 4) = sv;
        }
    }
    CFENCE();                                // gl published (cross-lane consumers)

    // ---- wide-gather lane constants (4 patches in ONE instr) ----
    const int  grp   = min(lane / 14, 3);    // patch (=pixel) slot
    const int  cp    = lane - grp * 14;
    const int  grow  = min(cp >> 1, 6);      // row 0..6
    const int  ghalf = cp & 1;               // 0: cols 0-3, 1: cols 3-6
    const bool gact  = lane < 56;
    const int  wsg   = max(0, min(WN - KS, ww0 + grp - 3));
    const int  rowoff = (hs + grow) * WN + ghalf * 3;

    float4 q;                                // single named in-flight reg
#define ISSUE(sp) { \
        int g_ = gl[grp * NSPN + (sp)]; \
        if (gact) __builtin_memcpy(&q, simsB + ((size_t)g_ << 14) + rowoff + wsg, 16); }
#define GSTORE(buf) { \
        if (gact) *(float4*)(pb + (buf) * PBUF + grp * PIXSTR + grow * 8 + ghalf * 4) = q; }

    ISSUE(0)                                 // in flight under staging + softmax

    // ---- attn staging: 4 aligned float4 rounds (one per hd-plane) ----
    const size_t hwk  = (size_t)HN * WN * KK;
    const size_t sbas = (size_t)(hh * WN + ww0) * KK;    // 16B-aligned (ww0%4==0)
    const float* aB   = attn + (size_t)b * HDN * hwk + sbas;

    {
        float4 t0, t1, t2, t3;
        if (lane < 49) {
            t0 = *(const float4*)(aB + lane * 4);
            t1 = *(const float4*)(aB + hwk + lane * 4);
            t2 = *(const float4*)(aB + 2 * hwk + lane * 4);
            t3 = *(const float4*)(aB + 3 * hwk + lane * 4);
            *(float4*)(stg + lane * 4) = t0;             // hd0 -> [0..195]
            *(float4*)(stg + 196 + lane * 4) = t1;
            *(float4*)(stg + 392 + lane * 4) = t2;
            *(float4*)(stg + 588 + lane * 4) = t3;
        }
    }
    CFENCE();                                // cross-lane RAW: stage -> a[] reads

    // ---- a[14]: per-lane redistribution (stride-49, ~2-way banks) ----
    const int abase = hd * 196 + pix * KK + s * 14;
    float a[14];
    #pragma unroll
    for (int j = 0; j < 14; ++j) {
        float v = -1e30f;                    // s3 ghosts: zero weight after exp
        if (s < 3 || j < 7) v = stg[abase + j];
        a[j] = v;
    }

    // ---- softmax: local max/exp + 4-lane butterfly ----
    {
        float m0 = fmaxf(a[0], a[1]),  m1 = fmaxf(a[2], a[3]);
        float m2 = fmaxf(a[4], a[5]),  m3 = fmaxf(a[6], a[7]);
        m0 = fmaxf(m0, fmaxf(a[8], a[9]));
        m1 = fmaxf(m1, fmaxf(a[10], a[11]));
        m2 = fmaxf(m2, fmaxf(a[12], a[13]));
        float m = fmaxf(fmaxf(m0, m1), fmaxf(m2, m3));
        m = fmaxf(m, __shfl_xor(m, 1));
        m = fmaxf(m, __shfl_xor(m, 2));      // unit max, identical in 4 lanes
        #pragma unroll
        for (int j = 0; j < 14; ++j) a[j] = __expf(a[j] - m);   // ghosts -> 0
    }

    GSTORE(0)

    // ---- compute-view constants ----
    const int prow0 = pix * PIXSTR + (2 * s) * 8;                  // row 2s quads
    const int prow1 = pix * PIXSTR + min(2 * s + 1, 6) * 8;        // row 2s+1 (s3: row6 again)
    const int wabs  = ww0 + pix;
    const int wsp   = max(0, min(WN - KS, wabs - 3));
    const int dc    = wabs - wsp;
    const int pioff = pix * PIXSTR + dr * 8 + dc + (dc > 3 ? 1 : 0);

    float acc[14];
    #pragma unroll
    for (int j = 0; j < 14; ++j) acc[j] = 0.0f;

    for (int sp = 0; sp < NSPN; ++sp) {
        const int buf = sp & 1;
        if (sp + 1 < NSPN) ISSUE(sp + 1)     // next plane in flight
        CFENCE();                            // RAW: gstore(prev)->reads; WAR: reads->gstore below

        const float* pp = pb + buf * PBUF;
        float4 p0 = *(const float4*)(pp + prow0);        // row r0 cols 0-3
        float4 p1 = *(const float4*)(pp + prow0 + 4);    // row r0 cols 3-6
        float4 p2 = *(const float4*)(pp + prow1);        // row r1 cols 0-3
        float4 p3 = *(const float4*)(pp + prow1 + 4);    // row r1 cols 3-6
        float pi  = pp[pioff];

        // partial denom over own 14 k (ghosts contribute 0), 2-way chains
        float d0 = a[0] * p0.x, d1 = a[1] * p0.y;
        d0 = fmaf(a[2],  p0.z, d0); d1 = fmaf(a[3],  p0.w, d1);
        d0 = fmaf(a[4],  p1.y, d0); d1 = fmaf(a[5],  p1.z, d1);
        d0 = fmaf(a[6],  p1.w, d0); d1 = fmaf(a[7],  p2.x, d1);
        d0 = fmaf(a[8],  p2.y, d0); d1 = fmaf(a[9],  p2.z, d1);
        d0 = fmaf(a[10], p2.w, d0); d1 = fmaf(a[11], p3.y, d1);
        d0 = fmaf(a[12], p3.z, d0); d1 = fmaf(a[13], p3.w, d1);
        float d = d0 + d1;
        d += __shfl_xor(d, 1);
        d += __shfl_xor(d, 2);               // full unit denom, identical in 4 lanes

        float coef = pi * __builtin_amdgcn_rcpf(d + 1e-10f);

        acc[0]  = fmaf(coef, p0.x, acc[0]);  acc[1]  = fmaf(coef, p0.y, acc[1]);
        acc[2]  = fmaf(coef, p0.z, acc[2]);  acc[3]  = fmaf(coef, p0.w, acc[3]);
        acc[4]  = fmaf(coef, p1.y, acc[4]);  acc[5]  = fmaf(coef, p1.z, acc[5]);
        acc[6]  = fmaf(coef, p1.w, acc[6]);  acc[7]  = fmaf(coef, p2.x, acc[7]);
        acc[8]  = fmaf(coef, p2.y, acc[8]);  acc[9]  = fmaf(coef, p2.z, acc[9]);
        acc[10] = fmaf(coef, p2.w, acc[10]); acc[11] = fmaf(coef, p3.y, acc[11]);
        acc[12] = fmaf(coef, p3.z, acc[12]); acc[13] = fmaf(coef, p3.w, acc[13]);

        if (sp + 1 < NSPN) GSTORE(buf ^ 1)   // in-wave order; no barrier
    }
#undef ISSUE
#undef GSTORE

    // ---- out: per-lane LDS stage (stride-49) -> 4 aligned float4 rounds ----
    CFENCE();                                // order: last patch/pi reads before stg overwrite
    #pragma unroll
    for (int j = 0; j < 14; ++j) {
        if (s < 3 || j < 7) stg[abase + j] = a[j] * acc[j];
    }
    CFENCE();                                // cross-lane RAW: writes -> float4 reads

    float* oB = out + (size_t)b * HDN * hwk + sbas;
    if (lane < 49) {
        float4 z0 = *(const float4*)(stg + lane * 4);
        float4 z1 = *(const float4*)(stg + 196 + lane * 4);
        float4 z2 = *(const float4*)(stg + 392 + lane * 4);
        float4 z3 = *(const float4*)(stg + 588 + lane * 4);
        *(float4*)(oB + lane * 4) = z0;
        *(float4*)(oB + hwk + lane * 4) = z1;
        *(float4*)(oB + 2 * hwk + lane * 4) = z2;
        *(float4*)(oB + 3 * hwk + lane * 4) = z3;
    }
}

extern "C" void kernel_launch(void* const* d_in, const int* in_sizes, int n_in,
                              void* d_out, int out_size, void* d_ws, size_t ws_size,
                              hipStream_t stream) {
    const float* attn  = (const float*)d_in[0];
    const float* sims  = (const float*)d_in[1];
    const int*   sinds = (const int*)d_in[2];
    float*       outp  = (float*)d_out;

    // blocks: b(2) x hh(128) x wseg(8) = 2048, 4 waves each (16 pixels/block)
    const int blocks = BN * HN * (WN / 16);
    attn_rw14<<<blocks, TPB, 0, stream>>>(attn, sims, sinds, outp);
}